// Round 6
// baseline (363.121 us; speedup 1.0000x reference)
//
#include <hip/hip_runtime.h>

typedef unsigned short u16;
typedef unsigned int u32;
typedef _Float16 f16;
typedef __attribute__((ext_vector_type(8))) _Float16 half8;
typedef __attribute__((ext_vector_type(2))) __fp16 fp16x2;
typedef __attribute__((ext_vector_type(4))) float float4_;
typedef __attribute__((ext_vector_type(4))) unsigned short ushort4_;
typedef __attribute__((ext_vector_type(4))) unsigned int u32x4;

union hu { f16 h; u16 u; };

__device__ __forceinline__ u32 pkrtz(float a, float b) {
    fp16x2 t = __builtin_amdgcn_cvt_pkrtz(a, b);
    union { fp16x2 h; u32 u; } cv; cv.h = t;
    return cv.u;
}

// ---------- async global->LDS, 16B/lane ----------
__device__ __forceinline__ void gl16(const u16* g, u16* l) {
    __builtin_amdgcn_global_load_lds(
        (const __attribute__((address_space(1))) void*)g,
        (__attribute__((address_space(3))) void*)l, 16, 0, 0);
}

#define Bsz 8
#define Tsz 4096
#define Csz 512
#define Usz 512
#define NG  1536           // 3U
#define KK  1024           // 2 taps * C
#define MM  32768          // B*T
#define NCH 64             // scan chunks
#define CHL 64             // chunk length

#define PA_BLKS 8194       // (8*4097*512/8)/256
#define PK_BLKS 6144       // 6*1024

// ---------- P: fused prep. Blocks [0,8194): A fp32->fp16 [8][4097][512] w/ zero row.
//             Blocks [8194, 8194+6144): K [1024][1536] -> KT fp16 [1536][1024]. ----------
__global__ void prep(const float* __restrict__ in, u16* __restrict__ A16,
                     const float* __restrict__ kern, u16* __restrict__ KT) {
    if (blockIdx.x < PA_BLKS) {
        int gid = blockIdx.x * 256 + threadIdx.x;       // 2,097,664 threads, 8 halves each
        int idx8 = gid * 8;
        int c8 = idx8 & 511;
        int row = idx8 >> 9;                            // b*4097 + t
        int b = (u32)row / 4097u;
        int t = row - b * 4097;
        u32x4 w;
        if (t == Tsz) {
            w = (u32x4)0;
        } else {
            const float* p = in + ((size_t)(b * Tsz + t) << 9) + c8;
            float4_ v0 = *(const float4_*)p;
            float4_ v1 = *(const float4_*)(p + 4);
            w.x = pkrtz(v0.x, v0.y); w.y = pkrtz(v0.z, v0.w);
            w.z = pkrtz(v1.x, v1.y); w.w = pkrtz(v1.z, v1.w);
        }
        *(u32x4*)(A16 + idx8) = w;
    } else {
        int bk = blockIdx.x - PA_BLKS;
        int k = bk / 6;
        int n = (bk % 6) * 256 + threadIdx.x;
        float v = kern[(size_t)k * NG + n];
        hu cv; cv.h = (f16)v;                 // RNE
        KT[(size_t)n * KK + k] = cv.u;
    }
}

// ---------- GEMM: gates = A'*K', fp16 MFMA, BK=64, XOR-swizzled LDS ----------
// A' row m = concat(A16[b][t], A16[b][t+1]); A16 padded layout makes the k-offset
// LINEAR (advancing 512 halves = tap+1), so staging addresses are base + kk.
__global__ __launch_bounds__(256, 4) void gemm_gates(
    const u16* __restrict__ A16, const u16* __restrict__ KT,
    const float* __restrict__ bias,
    u16* __restrict__ X, u16* __restrict__ F, u16* __restrict__ Oh,
    float* __restrict__ Of, int useOh)
{
    // Tiles [128 rows][64 halves]; 16B chunk c of row r stored at position c ^ (r&7)
    // -> every ds_read_b128 hits the 8-words/bank wave64 floor (R5: 0 conflicts).
    __shared__ u16 lA[8192], lB[8192];

    const int tid  = threadIdx.x;
    const int lane = tid & 63;
    const int wave = tid >> 6;

    // XCD-co-located swizzle: groups of 96 = 8 m-tiles x 12 n-sharers;
    // g = grp*96 + nb*8 + m_loc -> the 12 sharers of one A-tile are congruent mod 8
    // (same XCD under round-robin dispatch) -> A-tile stays in that XCD's L2.
    const int g    = blockIdx.x;
    const int grp  = g / 96;
    const int r    = g - grp * 96;
    const int mloc = r & 7;
    const int nb   = r >> 3;            // 0..11
    const int mb   = grp * 8 + mloc;
    const int m0 = mb * 128;
    const int n0 = nb * 128;
    const int b  = m0 >> 12;            // 128 | 4096 -> block never straddles batches
    const int t0 = m0 & 4095;
    const int arow0 = b * (Tsz + 1) + t0;

    float4_ acc[4][4];
    #pragma unroll
    for (int i = 0; i < 4; ++i)
        #pragma unroll
        for (int j = 0; j < 4; ++j) acc[i][j] = (float4_)0.0f;

    const int wm = (wave >> 1) * 64;
    const int wn = (wave & 1) * 64;
    const int ar = wm + (lane & 15);
    const int br = wn + (lane & 15);
    const int q  = lane >> 4;           // k-quad
    const int swz = lane & 7;

    // per-lane 32-bit base offsets, hoisted out of the K-loop (addresses linear in kk)
    u32 aOff[4], bOff[4];
    int ldsOff[4];
    #pragma unroll
    for (int it = 0; it < 4; ++it) {
        const int s = it * 256 + tid;          // chunk slot [0,1024)
        const int row = s >> 3, p = s & 7;
        const int c = p ^ (row & 7);
        aOff[it] = ((u32)(arow0 + row) << 9) + c * 8;
        bOff[it] = ((u32)(n0 + row) << 10) + c * 8;
        ldsOff[it] = (s - lane) * 8;           // wave-uniform
    }

    #pragma unroll 4
    for (int kk = 0; kk < KK; kk += 64) {
        __syncthreads();   // protect LDS from previous iteration's readers
        #pragma unroll
        for (int it = 0; it < 4; ++it)
            gl16(A16 + aOff[it] + kk, lA + ldsOff[it]);
        #pragma unroll
        for (int it = 0; it < 4; ++it)
            gl16(KT + bOff[it] + kk, lB + ldsOff[it]);
        __syncthreads();   // staging complete (barrier drains vmcnt)

        #pragma unroll
        for (int s2 = 0; s2 < 2; ++s2) {
            half8 fa[4], fb[4];
            const int cc = (s2 * 4 + q) ^ swz;     // swizzled chunk position
            #pragma unroll
            for (int i = 0; i < 4; ++i) {
                fa[i] = *(const half8*)(lA + (ar + i * 16) * 64 + cc * 8);
                fb[i] = *(const half8*)(lB + (br + i * 16) * 64 + cc * 8);
            }
            #pragma unroll
            for (int mi = 0; mi < 4; ++mi)
                #pragma unroll
                for (int ni = 0; ni < 4; ++ni)
                    acc[mi][ni] = __builtin_amdgcn_mfma_f32_16x16x32_f16(fa[mi], fb[ni], acc[mi][ni], 0, 0, 0);
        }
    }

    // epilogue: bias + activation. Plane uniform per block (128 | 512).
    const int plane = nb >> 2;   // 0=X,1=F,2=O
    const int rq = q * 4;
    const int cl = lane & 15;
    #pragma unroll
    for (int mi = 0; mi < 4; ++mi)
        #pragma unroll
        for (int ni = 0; ni < 4; ++ni) {
            const int gm = m0 + wm + mi * 16 + rq;
            const int gn = n0 + wn + ni * 16 + cl;
            const float bv = bias[gn];
            const int cp = gn & 511;
            #pragma unroll
            for (int r2 = 0; r2 < 4; ++r2) {
                float v = acc[mi][ni][r2] + bv;
                const size_t idx = (size_t)(gm + r2) * Usz + cp;
                if (plane == 0) {
                    float res = 1.0f - 2.0f / (__expf(2.0f * v) + 1.0f);   // tanh, overflow-safe
                    hu cv; cv.h = (f16)res;
                    X[idx] = cv.u;
                } else {
                    float res = 1.0f / (1.0f + __expf(-v));                // sigmoid, overflow-safe
                    if (plane == 1)      { hu cv; cv.h = (f16)res; F[idx] = cv.u; }
                    else if (useOh)      { hu cv; cv.h = (f16)res; Oh[idx] = cv.u; }
                    else                 { Of[idx] = res; }
                }
            }
        }
}

__device__ __forceinline__ float4_ x4(const u16* p) {
    ushort4_ xr = *(const ushort4_*)p;
    float4_ xv;
    #pragma unroll
    for (int j = 0; j < 4; ++j) { hu cv; cv.u = xr[j]; xv[j] = (float)cv.h; }
    return xv;
}

// ---------- S1: per-chunk composites A=prod f, B=chunk applied to c=0 ----------
__global__ void scan_chunk(const u16* __restrict__ F, const u16* __restrict__ X,
                           float* __restrict__ CA, float* __restrict__ CB) {
    int g = blockIdx.x * 256 + threadIdx.x;     // 65536 = B*NCH*U/4
    int u4 = (g & 127) * 4;
    int bc = g >> 7;                             // b*NCH + ch
    size_t base = (size_t)bc * CHL * Usz + u4;
    float4_ c = (float4_)0.0f, A = (float4_)1.0f;
    for (int i = 0; i < CHL; ++i) {
        float4_ fv = x4(F + base + (size_t)i * Usz);
        float4_ xv = x4(X + base + (size_t)i * Usz);
        c = fv * c + (1.0f - fv) * xv;
        A = A * fv;
    }
    *(float4_*)(CA + (size_t)bc * Usz + u4) = A;
    *(float4_*)(CB + (size_t)bc * Usz + u4) = c;
}

// ---------- S2: sequential prefix across chunks -> chunk-start carries ----------
__global__ void scan_prefix(const float* __restrict__ CA, const float* __restrict__ CB,
                            float* __restrict__ CS) {
    int g = blockIdx.x * 256 + threadIdx.x;     // 4096 = B*U
    int u = g & 511;
    int b = g >> 9;
    float c = 0.0f;
    #pragma unroll 16
    for (int ch = 0; ch < NCH; ++ch) {
        int idx = (b * NCH + ch) * Usz + u;
        CS[idx] = c;
        c = CA[idx] * c + CB[idx];
    }
}

// ---------- S3: re-scan chunks with carry, h = sigmoid(o)*c ----------
template <bool OH>
__global__ void scan_final(const u16* __restrict__ F, const u16* __restrict__ X,
                           const u16* __restrict__ Oh, const float* __restrict__ CS,
                           float* __restrict__ out) {
    int g = blockIdx.x * 256 + threadIdx.x;     // 65536
    int u4 = (g & 127) * 4;
    int bc = g >> 7;
    size_t base = (size_t)bc * CHL * Usz + u4;
    float4_ c = *(const float4_*)(CS + (size_t)bc * Usz + u4);
    for (int i = 0; i < CHL; ++i) {
        float4_ fv = x4(F + base + (size_t)i * Usz);
        float4_ xv = x4(X + base + (size_t)i * Usz);
        c = fv * c + (1.0f - fv) * xv;
        float4_ ov = OH ? x4(Oh + base + (size_t)i * Usz)
                        : *(const float4_*)(out + base + (size_t)i * Usz);  // read-before-write
        *(float4_*)(out + base + (size_t)i * Usz) = ov * c;
    }
}

extern "C" void kernel_launch(void* const* d_in, const int* in_sizes, int n_in,
                              void* d_out, int out_size, void* d_ws, size_t ws_size,
                              hipStream_t stream) {
    const float* in   = (const float*)d_in[0];   // [8,4096,512] fp32
    const float* kern = (const float*)d_in[1];   // [2,512,1536] fp32
    const float* bias = (const float*)d_in[2];   // [1536] fp32
    float* out = (float*)d_out;                  // [8,4096,512] fp32
    char* ws = (char*)d_ws;

    // workspace layout. Proven budget >= 110,102,528 (R2). Layout B (fp16 O plane)
    // is selected only if ws_size allows -> this round also probes the real budget.
    const size_t A16_B  = (size_t)Bsz * (Tsz + 1) * Csz * 2;   // 33,562,624
    const size_t OFF_KT = A16_B;
    const size_t OFF_F  = OFF_KT + (size_t)NG * KK * 2;        // 36,708,352
    const size_t OFF_X  = OFF_F + (size_t)MM * Usz * 2;        // 70,262,784
    const size_t OFF_O  = OFF_X + (size_t)MM * Usz * 2;        // 103,817,216
    const size_t CH_B   = (size_t)Bsz * NCH * Usz * 4;         //  1,048,576
    const size_t NEED_A = OFF_O + 3 * CH_B;                    // 106,962,944
    const size_t NEED_B = OFF_O + (size_t)MM * Usz * 2 + 3 * CH_B;  // 140,517,376

    if (ws_size < NEED_A) return;   // guard: fail-with-poison instead of OOB fault
    const int useOh = ws_size >= NEED_B;

    u16*   A16 = (u16*)ws;
    u16*   KT  = (u16*)(ws + OFF_KT);
    u16*   Fh  = (u16*)(ws + OFF_F);
    u16*   Xb  = (u16*)(ws + OFF_X);
    u16*   Ohp = (u16*)(ws + OFF_O);                 // layout B only
    const size_t caOff = useOh ? OFF_O + (size_t)MM * Usz * 2 : OFF_O;
    float* CA  = (float*)(ws + caOff);
    float* CB  = CA + CH_B / 4;
    float* CS  = CB + CH_B / 4;

    prep<<<PA_BLKS + PK_BLKS, 256, 0, stream>>>(in, A16, kern, KT);
    gemm_gates<<<(MM / 128) * (NG / 128), 256, 0, stream>>>(A16, KT, bias, Xb, Fh, Ohp, out, useOh);
    scan_chunk<<<Bsz * NCH * Usz / 4 / 256, 256, 0, stream>>>(Fh, Xb, CA, CB);
    scan_prefix<<<Bsz * Usz / 256, 256, 0, stream>>>(CA, CB, CS);
    if (useOh)
        scan_final<true><<<Bsz * NCH * Usz / 4 / 256, 256, 0, stream>>>(Fh, Xb, Ohp, CS, out);
    else
        scan_final<false><<<Bsz * NCH * Usz / 4 / 256, 256, 0, stream>>>(Fh, Xb, Ohp, CS, out);
}